// Round 5
// baseline (401.719 us; speedup 1.0000x reference)
//
#include <hip/hip_runtime.h>
#include <hip/hip_bf16.h>

// out[token][o] = scale * sum_k x[token][k]*W[o][k] - scale*zp*sum_k x[token][k] + bias[o]
// M=128, K=4096, N=16384. W int32 = 256 MiB -> memory-bound (~44us floor @6.3TB/s).
// v5: barrier-free streaming. One wave = one 16-row tile x all 128 tokens x full K.
// W is wave-private (read once GPU-wide) -> no LDS, no __syncthreads (which drains
// vmcnt(0) and killed v4). Register circular pipelines: W depth 8, B depth 2 ->
// ~64KB in flight per CU, compiler emits fine-grained vmcnt(N) (AITER pattern).
// x shared via L2 (1 MB bf16 frag image from prep_x). Per-wave K rotation.

#define IN_F 4096
#define OUT_F 16384
#define NTOK 128

typedef __attribute__((ext_vector_type(8))) short bf16x8;
typedef __attribute__((ext_vector_type(4))) float f32x4;

__device__ __forceinline__ unsigned short f32_to_bf16_rne(float f) {
  unsigned u = __float_as_uint(f);
  u += 0x7fffu + ((u >> 16) & 1u);
  return (unsigned short)(u >> 16);
}

// Pack x [128][4096] f32 -> bf16 fragment-major image in ws, plus per-token sums.
// chunk(s, t, lane) at uint4 index s*512 + t*64 + lane holds
//   x[token = t*16 + (lane&15)][k = s*32 + (lane>>4)*8 + j], j=0..7.
__global__ __launch_bounds__(512) void prep_x(const float* __restrict__ x,
                                              uint4* __restrict__ xf,
                                              float* __restrict__ xsum) {
  const int token = blockIdx.x;   // 0..127
  const int i = (int)threadIdx.x; // 0..511, handles k = i*8 .. i*8+7
  const int k0 = i << 3;
  const float4 v0 = *(const float4*)(x + token * IN_F + k0);
  const float4 v1 = *(const float4*)(x + token * IN_F + k0 + 4);
  float v[8] = {v0.x, v0.y, v0.z, v0.w, v1.x, v1.y, v1.z, v1.w};
  unsigned short h[8];
  float s = 0.f;
#pragma unroll
  for (int j = 0; j < 8; ++j) {
    s += v[j];
    h[j] = f32_to_bf16_rne(v[j]);
  }
  uint4 o;
  o.x = (unsigned)h[0] | ((unsigned)h[1] << 16);
  o.y = (unsigned)h[2] | ((unsigned)h[3] << 16);
  o.z = (unsigned)h[4] | ((unsigned)h[5] << 16);
  o.w = (unsigned)h[6] | ((unsigned)h[7] << 16);
  const int slab = i >> 2;
  const int q = i & 3;
  const int lane = (q << 4) | (token & 15);
  xf[slab * 512 + (token >> 4) * 64 + lane] = o;

#pragma unroll
  for (int off = 32; off > 0; off >>= 1) s += __shfl_down(s, off, 64);
  __shared__ float wsum[8];
  if ((i & 63) == 0) wsum[i >> 6] = s;
  __syncthreads();
  if (i == 0) {
    float t = 0.f;
#pragma unroll
    for (int a = 0; a < 8; ++a) t += wsum[a];
    xsum[token] = t;
  }
}

// int in [-127,127] -> f32 exact, zero low-16 mantissa -> bf16 truncation is EXACT.
__device__ __forceinline__ bf16x8 cvt8(int4 a, int4 b) {
  bf16x8 o;
  o[0] = (short)(__float_as_uint((float)a.x) >> 16);
  o[1] = (short)(__float_as_uint((float)a.y) >> 16);
  o[2] = (short)(__float_as_uint((float)a.z) >> 16);
  o[3] = (short)(__float_as_uint((float)a.w) >> 16);
  o[4] = (short)(__float_as_uint((float)b.x) >> 16);
  o[5] = (short)(__float_as_uint((float)b.y) >> 16);
  o[6] = (short)(__float_as_uint((float)b.z) >> 16);
  o[7] = (short)(__float_as_uint((float)b.w) >> 16);
  return o;
}

// One wave per block (64 threads), grid = 1024 row-tiles. No LDS, no barriers.
// Lane(q=l>>4, r=l&15): A-frag for k-step kk = W[R0+r][kk*32 + q*8 .. +7] (2 int4,
// 4 q-lanes cover a full 128B line per row). B-frag tile t from xf (coalesced 1KB).
// Per k-step: 8 B-loads + 2 W-loads + cvt + 8 MFMA. W pipe depth 8, B pipe depth 2.
__global__ __launch_bounds__(64, 1) void qlinear_main(
    const int* __restrict__ W, const uint4* __restrict__ xf,
    const float* __restrict__ xsum, const float* __restrict__ scale_p,
    const float* __restrict__ zp_p, const float* __restrict__ bias,
    float* __restrict__ out) {
  const int l = (int)threadIdx.x;
  const int q = l >> 4;
  const int r = l & 15;
  const int rt = (int)blockIdx.x;   // row-tile 0..1023
  const int R0 = rt * 16;

  const int* Wbase = W + (R0 + r) * IN_F + q * 8;
  const int start = (rt * 37) & 127;  // per-wave K rotation (DRAM channel spread)

  int4 wa[8], wb[8];   // W pipe (depth 8): slot d holds step (k where k%8==d)
  uint4 bb[2][8];      // B pipe (depth 2): parity-indexed

  f32x4 acc[8];
#pragma unroll
  for (int t = 0; t < 8; ++t) acc[t] = (f32x4)0.0f;

  // prime W pipe: steps 0..7
#pragma unroll
  for (int d = 0; d < 8; ++d) {
    const int kk = (start + d) & 127;
    wa[d] = *(const int4*)(Wbase + kk * 32);
    wb[d] = *(const int4*)(Wbase + kk * 32 + 4);
  }
  // prime B pipe: steps 0..1
#pragma unroll
  for (int d = 0; d < 2; ++d) {
    const int kk = (start + d) & 127;
    const uint4* xp = xf + kk * 512 + l;
#pragma unroll
    for (int t = 0; t < 8; ++t) bb[d][t] = xp[t * 64];
  }

  // main: steps 0..119, refilling W step+8 (max 127) and B step+2 (max 121)
#pragma unroll 1
  for (int k = 0; k <= 112; k += 8) {
#pragma unroll
    for (int u = 0; u < 8; ++u) {
      const int step = k + u;
      // refill B for step+2 (same parity slot as step)
      {
        const int kk = (start + step + 2) & 127;
        const uint4* xp = xf + kk * 512 + l;
        uint4 nb0 = xp[0 * 64], nb1 = xp[1 * 64], nb2 = xp[2 * 64], nb3 = xp[3 * 64];
        uint4 nb4 = xp[4 * 64], nb5 = xp[5 * 64], nb6 = xp[6 * 64], nb7 = xp[7 * 64];
        // refill W for step+8 into slot u (consume current first)
        const int kw = (start + step + 8) & 127;
        int4 nwa = *(const int4*)(Wbase + kw * 32);
        int4 nwb = *(const int4*)(Wbase + kw * 32 + 4);
        bf16x8 a = cvt8(wa[u], wb[u]);
        wa[u] = nwa;
        wb[u] = nwb;
#pragma unroll
        for (int t = 0; t < 8; ++t) {
          bf16x8 b = *(const bf16x8*)&bb[u & 1][t];
          acc[t] = __builtin_amdgcn_mfma_f32_16x16x32_bf16(a, b, acc[t], 0, 0, 0);
        }
        bb[u & 1][0] = nb0; bb[u & 1][1] = nb1; bb[u & 1][2] = nb2; bb[u & 1][3] = nb3;
        bb[u & 1][4] = nb4; bb[u & 1][5] = nb5; bb[u & 1][6] = nb6; bb[u & 1][7] = nb7;
      }
    }
  }
  // tail: steps 120..127, no W refill; B refill for steps 122..127 (u < 6)
#pragma unroll
  for (int u = 0; u < 8; ++u) {
    const int step = 120 + u;
    bf16x8 a = cvt8(wa[u], wb[u]);
    if (u < 6) {
      const int kk = (start + step + 2) & 127;
      const uint4* xp = xf + kk * 512 + l;
      uint4 nb[8];
#pragma unroll
      for (int t = 0; t < 8; ++t) nb[t] = xp[t * 64];
#pragma unroll
      for (int t = 0; t < 8; ++t) {
        bf16x8 b = *(const bf16x8*)&bb[u & 1][t];
        acc[t] = __builtin_amdgcn_mfma_f32_16x16x32_bf16(a, b, acc[t], 0, 0, 0);
      }
#pragma unroll
      for (int t = 0; t < 8; ++t) bb[u & 1][t] = nb[t];
    } else {
#pragma unroll
      for (int t = 0; t < 8; ++t) {
        bf16x8 b = *(const bf16x8*)&bb[u & 1][t];
        acc[t] = __builtin_amdgcn_mfma_f32_16x16x32_bf16(a, b, acc[t], 0, 0, 0);
      }
    }
  }

  // ---- epilogue: D layout col=lane&15 -> token-in-tile, row=q*4+e -> feature ----
  const float scale = *scale_p;
  const float zp = *zp_p;
  const float czp = scale * zp;
  const float4 bv = *(const float4*)(bias + R0 + q * 4);
#pragma unroll
  for (int t = 0; t < 8; ++t) {
    const int token = t * 16 + r;
    const float corr = -czp * xsum[token];
    float4 o;
    o.x = acc[t][0] * scale + corr + bv.x;
    o.y = acc[t][1] * scale + corr + bv.y;
    o.z = acc[t][2] * scale + corr + bv.z;
    o.w = acc[t][3] * scale + corr + bv.w;
    *(float4*)(out + token * OUT_F + R0 + q * 4) = o;
  }
}

extern "C" void kernel_launch(void* const* d_in, const int* in_sizes, int n_in,
                              void* d_out, int out_size, void* d_ws, size_t ws_size,
                              hipStream_t stream) {
  const float* x = (const float*)d_in[0];        // [8,16,4096] f32
  const int* W = (const int*)d_in[1];            // [16384,4096] int32
  const float* scale = (const float*)d_in[2];    // scalar
  const float* zp = (const float*)d_in[3];       // scalar
  const float* bias = (const float*)d_in[4];     // [16384] f32
  float* out = (float*)d_out;                    // [8,16,16384] f32

  uint4* xf = (uint4*)d_ws;                              // 1 MiB bf16 frag image
  float* xsum = (float*)((char*)d_ws + (1 << 20));       // 128 floats

  prep_x<<<NTOK, 512, 0, stream>>>(x, xf, xsum);
  // 1024 row-tiles, one wave each (64 threads). ~4 waves/CU, no LDS, no barriers.
  qlinear_main<<<OUT_F / 16, 64, 0, stream>>>(W, xf, xsum, scale, zp, bias, out);
}

// Round 6
// 385.790 us; speedup vs baseline: 1.0413x; 1.0413x over previous
//
#include <hip/hip_runtime.h>
#include <hip/hip_bf16.h>

// out[token][o] = scale * sum_k x[token][k]*W[o][k] - scale*zp*sum_k x[token][k] + bias[o]
// M=128, K=4096, N=16384. W int32 = 256 MiB -> memory-bound (~44us floor @6.3TB/s).
// v6: barrier-free streaming with 32x32x16 MFMA. Block = 32 rows x 256 thr (4 waves =
// 4 K-quarters), 512 blocks -> 8 waves/CU. Per wave per k16-step: 2 W int4 + 4 B uint4
// loads (6 VMEM -> 48 outstanding at consume < vmcnt cap 63; v5 had 80 -> stalls),
// register pipes W depth 8 / B depth 2, no __syncthreads until the end reduction.
// B traffic halved vs v5 (32-row tiles double B reuse).

#define IN_F 4096
#define OUT_F 16384
#define NTOK 128

typedef __attribute__((ext_vector_type(8))) short bf16x8;
typedef __attribute__((ext_vector_type(4))) float f32x4;
typedef __attribute__((ext_vector_type(16))) float f32x16;

__device__ __forceinline__ unsigned short f32_to_bf16_rne(float f) {
  unsigned u = __float_as_uint(f);
  u += 0x7fffu + ((u >> 16) & 1u);
  return (unsigned short)(u >> 16);
}

// Pack x [128][4096] f32 -> bf16 image for 32x32x16 B-frags, plus per-token sums.
// uint4 at index (S*4 + t)*64 + lane holds x[token = t*32 + (lane&31)]
// [k = S*16 + (lane>>5)*8 + j], j=0..7.  S = k16 step 0..255, t = token tile 0..3.
__global__ __launch_bounds__(512) void prep_x(const float* __restrict__ x,
                                              uint4* __restrict__ xf,
                                              float* __restrict__ xsum) {
  const int token = blockIdx.x;   // 0..127
  const int i = (int)threadIdx.x; // 0..511, handles k = i*8 .. i*8+7
  const int k0 = i << 3;
  const float4 v0 = *(const float4*)(x + token * IN_F + k0);
  const float4 v1 = *(const float4*)(x + token * IN_F + k0 + 4);
  float v[8] = {v0.x, v0.y, v0.z, v0.w, v1.x, v1.y, v1.z, v1.w};
  unsigned short h[8];
  float s = 0.f;
#pragma unroll
  for (int j = 0; j < 8; ++j) {
    s += v[j];
    h[j] = f32_to_bf16_rne(v[j]);
  }
  uint4 o;
  o.x = (unsigned)h[0] | ((unsigned)h[1] << 16);
  o.y = (unsigned)h[2] | ((unsigned)h[3] << 16);
  o.z = (unsigned)h[4] | ((unsigned)h[5] << 16);
  o.w = (unsigned)h[6] | ((unsigned)h[7] << 16);
  const int S = i >> 1;          // k16 step
  const int half = i & 1;        // (k0 % 16) / 8
  const int t = token >> 5;      // token tile
  const int lane = half * 32 + (token & 31);
  xf[(S * 4 + t) * 64 + lane] = o;

#pragma unroll
  for (int off = 32; off > 0; off >>= 1) s += __shfl_down(s, off, 64);
  __shared__ float wsum[8];
  if ((i & 63) == 0) wsum[i >> 6] = s;
  __syncthreads();
  if (i == 0) {
    float t2 = 0.f;
#pragma unroll
    for (int a = 0; a < 8; ++a) t2 += wsum[a];
    xsum[token] = t2;
  }
}

// int in [-127,127] -> f32 exact, zero low-16 mantissa -> bf16 truncation is EXACT.
__device__ __forceinline__ bf16x8 cvt8(int4 a, int4 b) {
  bf16x8 o;
  o[0] = (short)(__float_as_uint((float)a.x) >> 16);
  o[1] = (short)(__float_as_uint((float)a.y) >> 16);
  o[2] = (short)(__float_as_uint((float)a.z) >> 16);
  o[3] = (short)(__float_as_uint((float)a.w) >> 16);
  o[4] = (short)(__float_as_uint((float)b.x) >> 16);
  o[5] = (short)(__float_as_uint((float)b.y) >> 16);
  o[6] = (short)(__float_as_uint((float)b.z) >> 16);
  o[7] = (short)(__float_as_uint((float)b.w) >> 16);
  return o;
}

// Grid 512 blocks x 256 threads. Block = rows R0..R0+31; wave w = K-quarter
// (1024 ints = 64 k16-steps). A-lane: row = lane&31, k-chunk = (lane>>5)*8.
// acc: 4 token-tiles x f32x16. End: 4-way K reduction via 64KB LDS (one barrier).
__global__ __launch_bounds__(256, 2) void qlinear_main(
    const int* __restrict__ W, const uint4* __restrict__ xf,
    const float* __restrict__ xsum, const float* __restrict__ scale_p,
    const float* __restrict__ zp_p, const float* __restrict__ bias,
    float* __restrict__ out) {
  __shared__ f32x4 red[4 * 1024];  // 64 KB, epilogue only

  const int tid = (int)threadIdx.x;
  const int w = tid >> 6;   // K quarter 0..3
  const int l = tid & 63;
  const int row = l & 31;
  const int hb = l >> 5;    // k-half within k16
  const int rt = (int)blockIdx.x;
  const int R0 = rt * 32;

  const int* Wbase = W + (R0 + row) * IN_F + w * 1024 + hb * 8;
  const uint4* xfb = xf + l;
  const int s0 = (rt * 13) & 63;  // K rotation within quarter (channel spread)

  int4 wa[8], wb[8];   // W pipe depth 8 (k16 steps)
  uint4 bb[2][4];      // B pipe depth 2, 4 token tiles

  f32x16 acc[4];
#pragma unroll
  for (int t = 0; t < 4; ++t) acc[t] = (f32x16)0.0f;

  // prime W pipe (steps 0..7) and B pipe (steps 0..1)
#pragma unroll
  for (int d = 0; d < 8; ++d) {
    const int ss = (s0 + d) & 63;
    wa[d] = *(const int4*)(Wbase + ss * 16);
    wb[d] = *(const int4*)(Wbase + ss * 16 + 4);
  }
#pragma unroll
  for (int d = 0; d < 2; ++d) {
    const int S = w * 64 + ((s0 + d) & 63);
#pragma unroll
    for (int t = 0; t < 4; ++t) bb[d][t] = xfb[(S * 4 + t) * 64];
  }

  // main: steps 0..55 (refill W s+8, B s+2)
#pragma unroll 1
  for (int it = 0; it < 7; ++it) {
#pragma unroll
    for (int u = 0; u < 8; ++u) {
      const int s = it * 8 + u;
      const int Sn = w * 64 + ((s0 + s + 2) & 63);
      uint4 nb0 = xfb[(Sn * 4 + 0) * 64];
      uint4 nb1 = xfb[(Sn * 4 + 1) * 64];
      uint4 nb2 = xfb[(Sn * 4 + 2) * 64];
      uint4 nb3 = xfb[(Sn * 4 + 3) * 64];
      const int ssw = (s0 + s + 8) & 63;
      int4 nwa = *(const int4*)(Wbase + ssw * 16);
      int4 nwb = *(const int4*)(Wbase + ssw * 16 + 4);
      bf16x8 a = cvt8(wa[u], wb[u]);
      acc[0] = __builtin_amdgcn_mfma_f32_32x32x16_bf16(a, *(const bf16x8*)&bb[u & 1][0], acc[0], 0, 0, 0);
      acc[1] = __builtin_amdgcn_mfma_f32_32x32x16_bf16(a, *(const bf16x8*)&bb[u & 1][1], acc[1], 0, 0, 0);
      acc[2] = __builtin_amdgcn_mfma_f32_32x32x16_bf16(a, *(const bf16x8*)&bb[u & 1][2], acc[2], 0, 0, 0);
      acc[3] = __builtin_amdgcn_mfma_f32_32x32x16_bf16(a, *(const bf16x8*)&bb[u & 1][3], acc[3], 0, 0, 0);
      wa[u] = nwa; wb[u] = nwb;
      bb[u & 1][0] = nb0; bb[u & 1][1] = nb1; bb[u & 1][2] = nb2; bb[u & 1][3] = nb3;
    }
  }
  // tail: steps 56..63 (no W refill; B refill only while s+2 <= 63)
#pragma unroll
  for (int u = 0; u < 8; ++u) {
    const int s = 56 + u;
    bf16x8 a = cvt8(wa[u], wb[u]);
    if (u < 6) {
      const int Sn = w * 64 + ((s0 + s + 2) & 63);
      uint4 nb0 = xfb[(Sn * 4 + 0) * 64];
      uint4 nb1 = xfb[(Sn * 4 + 1) * 64];
      uint4 nb2 = xfb[(Sn * 4 + 2) * 64];
      uint4 nb3 = xfb[(Sn * 4 + 3) * 64];
      acc[0] = __builtin_amdgcn_mfma_f32_32x32x16_bf16(a, *(const bf16x8*)&bb[u & 1][0], acc[0], 0, 0, 0);
      acc[1] = __builtin_amdgcn_mfma_f32_32x32x16_bf16(a, *(const bf16x8*)&bb[u & 1][1], acc[1], 0, 0, 0);
      acc[2] = __builtin_amdgcn_mfma_f32_32x32x16_bf16(a, *(const bf16x8*)&bb[u & 1][2], acc[2], 0, 0, 0);
      acc[3] = __builtin_amdgcn_mfma_f32_32x32x16_bf16(a, *(const bf16x8*)&bb[u & 1][3], acc[3], 0, 0, 0);
      bb[u & 1][0] = nb0; bb[u & 1][1] = nb1; bb[u & 1][2] = nb2; bb[u & 1][3] = nb3;
    } else {
      acc[0] = __builtin_amdgcn_mfma_f32_32x32x16_bf16(a, *(const bf16x8*)&bb[u & 1][0], acc[0], 0, 0, 0);
      acc[1] = __builtin_amdgcn_mfma_f32_32x32x16_bf16(a, *(const bf16x8*)&bb[u & 1][1], acc[1], 0, 0, 0);
      acc[2] = __builtin_amdgcn_mfma_f32_32x32x16_bf16(a, *(const bf16x8*)&bb[u & 1][2], acc[2], 0, 0, 0);
      acc[3] = __builtin_amdgcn_mfma_f32_32x32x16_bf16(a, *(const bf16x8*)&bb[u & 1][3], acc[3], 0, 0, 0);
    }
  }

  // ---- K reduction across 4 waves + epilogue ----
#pragma unroll
  for (int t = 0; t < 4; ++t)
#pragma unroll
    for (int g = 0; g < 4; ++g) {
      f32x4 v;
      v[0] = acc[t][g * 4 + 0]; v[1] = acc[t][g * 4 + 1];
      v[2] = acc[t][g * 4 + 2]; v[3] = acc[t][g * 4 + 3];
      red[w * 1024 + (t * 4 + g) * 64 + l] = v;
    }
  __syncthreads();  // single drain at kernel end — pipeline already done

  const float scale = *scale_p;
  const float zp = *zp_p;
  const float czp = scale * zp;
#pragma unroll
  for (int j = 0; j < 4; ++j) {
    const int c = j * 256 + tid;  // 0..1023
    const int chunk = c >> 6;     // (t*4 + g)
    const int ln = c & 63;
    f32x4 sum = red[chunk * 64 + ln] + red[1024 + chunk * 64 + ln] +
                red[2048 + chunk * 64 + ln] + red[3072 + chunk * 64 + ln];
    const int t = chunk >> 2;
    const int g = chunk & 3;
    const int col = ln & 31;
    const int half = ln >> 5;
    const int token = t * 32 + col;                 // D: col = lane&31 -> token
    const int feat = R0 + 8 * g + 4 * half;         // D: row = e + 8g + 4*half
    const float corr = -czp * xsum[token];
    const float4 bv = *(const float4*)(bias + feat);
    float4 o;
    o.x = sum[0] * scale + corr + bv.x;
    o.y = sum[1] * scale + corr + bv.y;
    o.z = sum[2] * scale + corr + bv.z;
    o.w = sum[3] * scale + corr + bv.w;
    *(float4*)(out + token * OUT_F + feat) = o;
  }
}

extern "C" void kernel_launch(void* const* d_in, const int* in_sizes, int n_in,
                              void* d_out, int out_size, void* d_ws, size_t ws_size,
                              hipStream_t stream) {
  const float* x = (const float*)d_in[0];        // [8,16,4096] f32
  const int* W = (const int*)d_in[1];            // [16384,4096] int32
  const float* scale = (const float*)d_in[2];    // scalar
  const float* zp = (const float*)d_in[3];       // scalar
  const float* bias = (const float*)d_in[4];     // [16384] f32
  float* out = (float*)d_out;                    // [8,16,16384] f32

  uint4* xf = (uint4*)d_ws;                              // 1 MiB bf16 frag image
  float* xsum = (float*)((char*)d_ws + (1 << 20));       // 128 floats

  prep_x<<<NTOK, 512, 0, stream>>>(x, xf, xsum);
  // 512 row-tile blocks (32 rows each) x 256 threads (4 K-quarter waves).
  qlinear_main<<<OUT_F / 32, 256, 0, stream>>>(W, xf, xsum, scale, zp, bias, out);
}